// Round 14
// baseline (318.549 us; speedup 1.0000x reference)
//
#include <hip/hip_runtime.h>
#include <cstdint>
#include <cstddef>

#define NLVL 4
#define TSIZE (1u << 19)
#define NH 64
#define NOUT 128
#define MBLK 128           // points per tile; 8 waves x 16 points
#define TILES 4            // tiles per workgroup (pipelined)
#define PANEL 12800        // f16 elems per level panel: WsA 4096 | Ff 512 | WoB 8192
#define SFOLD 4.774648292756860f   // 30/(2*pi), folded into Ws/Wout/bs/bout

typedef _Float16 f16x8 __attribute__((ext_vector_type(8)));
typedef _Float16 f16x2 __attribute__((ext_vector_type(2)));
typedef float f32x4 __attribute__((ext_vector_type(4)));
typedef unsigned short u16x8 __attribute__((ext_vector_type(8)));
typedef unsigned int u32x4 __attribute__((ext_vector_type(4)));

// sin(2*pi*x): fract then v_sin (input in revolutions)
__device__ __forceinline__ float fsin01(float x) {
    return __builtin_amdgcn_sinf(__builtin_amdgcn_fractf(x));
}
__device__ __forceinline__ unsigned short h2u(_Float16 h) {
    return __builtin_bit_cast(unsigned short, h);
}
__device__ __forceinline__ unsigned int pk16(float a, float b) {
    return __builtin_bit_cast(unsigned int, __builtin_amdgcn_cvt_pkrtz(a, b));
}
// async global->LDS, 16B per lane; lds dest = wave-uniform base + lane*16
__device__ __forceinline__ void gl_lds16(const _Float16* g, _Float16* l) {
    __builtin_amdgcn_global_load_lds(
        (const __attribute__((address_space(1))) void*)g,
        (__attribute__((address_space(3))) void*)l, 16, 0, 0);
}

// ---- prep 1: weights -> per-level packed panels in d_ws (f16), scales folded ----
__global__ void prep_weights(const float* __restrict__ Ws,
                             const float* __restrict__ Wout,
                             const float* __restrict__ ffn,
                             _Float16* __restrict__ ws)
{
    int i = blockIdx.x * 256 + threadIdx.x;
    if (i < 16384) {                       // Ws [4][64 k][64 c]
        int l = i >> 12, r = i & 4095, k = r >> 6, c = r & 63;
        ws[l * PANEL + ((c * 64 + k) ^ ((c & 7) << 3))] = (_Float16)(Ws[i] * SFOLD);
    } else if (i < 18432) {                // ffn [4][8 k][64 c]
        int j = i - 16384;
        int l = j >> 9, r = j & 511, k = r >> 6, c = r & 63;
        ws[l * PANEL + 4096 + c * 8 + k] = (_Float16)(ffn[j] * 0.000244140625f);
    } else if (i < 51200) {                // Wout [4][64 k][128 c]
        int j = i - 18432;
        int l = j >> 13, rem = j & 8191, k = rem >> 7, c = rem & 127;
        int ct = c >> 4, r15 = c & 15, kb = k >> 5, hi4 = (k >> 3) & 3, jj = k & 7;
        ws[l * PANEL + 4608 + (ct * 2 + kb) * 512 + hi4 * 128 + r15 * 8 + jj] =
            (_Float16)(Wout[j] * SFOLD);
    }
}

// ---- prep 2: table f32 -> f16 * 4096 (denormal protection; halves gather bytes) ----
__global__ __launch_bounds__(256) void prep_table(const float* __restrict__ table,
                                                  _Float16* __restrict__ tab16)
{
    int i = blockIdx.x * 256 + threadIdx.x;            // 16,777,216 elems
    float v = __builtin_nontemporal_load(table + i);
    tab16[i] = (_Float16)(v * 4096.f);
}

// F16TAB true: pipelined register-prefetch gather from tab16. false: f32 fallback.
template <bool F16TAB>
__global__ __launch_bounds__(512, 2)
void ffb_main(const float* __restrict__ in_pos,
              const float* __restrict__ table,
              const _Float16* __restrict__ tab16,
              const float* __restrict__ W0,
              const float* __restrict__ b0,
              const float* __restrict__ bs,
              const float* __restrict__ bout,
              const _Float16* __restrict__ wsg,
              float* __restrict__ out)
{
    __shared__ __align__(16) _Float16 wbuf[2][PANEL];            // 51200 B dbuf panels
    __shared__ __align__(16) unsigned short gS[2][NLVL][MBLK][8];// 16384 B dbuf g*4096

    const int tid = threadIdx.x;
    const int blkbase = blockIdx.x * (MBLK * TILES);
    const int lane = tid & 63;
    const int wv = tid >> 6;
    const int r15 = lane & 15;
    const int hi4 = lane >> 4;

    // gather role: one (point, level) per thread
    const int p_g = tid & (MBLK - 1);
    const int lv_g = tid >> 7;
    const uint32_t P1 = 2654435761u, P2 = 805459861u;

    u16x8 vv[8];               // in-flight gather lines (held across compute)
    float gfx, gfy, gfz;       // trilinear fractions for deferred interp

    // issue 8 independent 16B loads for tile at pb; interp deferred
    auto issueGather = [&](int pb) {
        const float px = in_pos[3 * (pb + p_g) + 0];
        const float py = in_pos[3 * (pb + p_g) + 1];
        const float pz = in_pos[3 * (pb + p_g) + 2];
        const float res = (float)(16 << lv_g);
        float gx = (px + 1.f) * 0.5f * res;
        float gy = (py + 1.f) * 0.5f * res;
        float gz = (pz + 1.f) * 0.5f * res;
        float fx0 = floorf(gx), fy0 = floorf(gy), fz0 = floorf(gz);
        gfx = gx - fx0; gfy = gy - fy0; gfz = gz - fz0;
        uint32_t ux = (uint32_t)fx0, uy = (uint32_t)fy0, uz = (uint32_t)fz0;
        uint32_t hx0 = ux, hx1 = ux + 1u;
        uint32_t hy0 = uy * P1, hy1 = hy0 + P1;
        uint32_t hz0 = uz * P2, hz1 = hz0 + P2;
        const _Float16* tl = tab16 + (size_t)lv_g * TSIZE * 8;
        #pragma unroll
        for (int c = 0; c < 8; ++c) {
            uint32_t h = (((c & 4) ? hx1 : hx0) ^ ((c & 2) ? hy1 : hy0)
                          ^ ((c & 1) ? hz1 : hz0)) & (TSIZE - 1u);
            vv[c] = *(const u16x8*)(tl + (size_t)h * 8);
        }
    };
    // consume vv -> gS[slot]
    auto interpStore = [&](int slot) {
        f16x2 acc2[4];
        #pragma unroll
        for (int q = 0; q < 4; ++q) acc2[q] = (f16x2){(_Float16)0.f, (_Float16)0.f};
        #pragma unroll
        for (int c = 0; c < 8; ++c) {
            float w = ((c & 4) ? gfx : 1.f - gfx) * ((c & 2) ? gfy : 1.f - gfy)
                    * ((c & 1) ? gfz : 1.f - gfz);
            _Float16 wh = (_Float16)w;
            f16x2 ww = {wh, wh};
            const f16x2* vp = (const f16x2*)&vv[c];
            #pragma unroll
            for (int q = 0; q < 4; ++q) acc2[q] = acc2[q] + ww * vp[q];  // v_pk_fma_f16
        }
        *(u16x8*)&gS[slot][lv_g][p_g][0] = *(u16x8*)&acc2[0];
    };
    // fallback: f32 table, gather+interp inline (not pipelined)
    auto gatherF32 = [&](int pb, int slot) {
        const float px = in_pos[3 * (pb + p_g) + 0];
        const float py = in_pos[3 * (pb + p_g) + 1];
        const float pz = in_pos[3 * (pb + p_g) + 2];
        const float res = (float)(16 << lv_g);
        float gx = (px + 1.f) * 0.5f * res;
        float gy = (py + 1.f) * 0.5f * res;
        float gz = (pz + 1.f) * 0.5f * res;
        float fx0 = floorf(gx), fy0 = floorf(gy), fz0 = floorf(gz);
        float fx = gx - fx0, fy = gy - fy0, fz = gz - fz0;
        uint32_t ux = (uint32_t)fx0, uy = (uint32_t)fy0, uz = (uint32_t)fz0;
        uint32_t hx0 = ux, hx1 = ux + 1u;
        uint32_t hy0 = uy * P1, hy1 = hy0 + P1;
        uint32_t hz0 = uz * P2, hz1 = hz0 + P2;
        const float* tl = table + (size_t)lv_g * TSIZE * 8;
        float g[8];
        #pragma unroll
        for (int q = 0; q < 8; ++q) g[q] = 0.f;
        #pragma unroll
        for (int c = 0; c < 8; ++c) {
            uint32_t h = (((c & 4) ? hx1 : hx0) ^ ((c & 2) ? hy1 : hy0)
                          ^ ((c & 1) ? hz1 : hz0)) & (TSIZE - 1u);
            float w = ((c & 4) ? fx : 1.f - fx) * ((c & 2) ? fy : 1.f - fy)
                    * ((c & 1) ? fz : 1.f - fz);
            const float4* fp = (const float4*)(tl + (size_t)h * 8);
            float4 va = fp[0], vb = fp[1];
            g[0] = fmaf(w, va.x, g[0]); g[1] = fmaf(w, va.y, g[1]);
            g[2] = fmaf(w, va.z, g[2]); g[3] = fmaf(w, va.w, g[3]);
            g[4] = fmaf(w, vb.x, g[4]); g[5] = fmaf(w, vb.y, g[5]);
            g[6] = fmaf(w, vb.z, g[6]); g[7] = fmaf(w, vb.w, g[7]);
        }
        u16x8 gv;
        #pragma unroll
        for (int q = 0; q < 8; ++q)
            gv[q] = h2u((_Float16)(g[q] * 4096.f));
        *(u16x8*)&gS[slot][lv_g][p_g][0] = gv;
    };

    // async panel staging; dst alternates via l&1, wraps across tiles
    auto stage = [&](int l) {
        const _Float16* src = wsg + l * PANEL;
        _Float16* dst = &wbuf[l & 1][0];
        #pragma unroll
        for (int i = 0; i < 3; ++i)
            gl_lds16(src + (i * 512 + tid) * 8, dst + (i * 512 + (tid & ~63)) * 8);
        if (tid < 64)
            gl_lds16(src + (1536 + tid) * 8, dst + 1536 * 8);
    };

    // layer0 -> B-frags (folded: sin(30a) = fsin01(a*S))
    f16x8 Xb[2];
    auto layer0 = [&](int pb) {
        const int pp = pb + wv * 16 + r15;
        const float lpx = in_pos[3 * pp + 0];
        const float lpy = in_pos[3 * pp + 1];
        const float lpz = in_pos[3 * pp + 2];
        #pragma unroll
        for (int kb = 0; kb < 2; ++kb) {
            f16x8 v;
            #pragma unroll
            for (int j = 0; j < 8; ++j) {
                const int f = kb * 32 + hi4 * 8 + j;
                float a = b0[f] + lpx * W0[f] + lpy * W0[64 + f] + lpz * W0[128 + f];
                v[j] = (_Float16)fsin01(a * SFOLD);
            }
            Xb[kb] = v;
        }
    };

    // ---------- prologue: tile 0 ----------
    if (F16TAB) issueGather(blkbase);
    stage(0);
    if (F16TAB) interpStore(0); else gatherF32(blkbase, 0);
    layer0(blkbase);
    __syncthreads();   // gS[0] + panel0 visible

    // bpermute indices (byte addressing)
    const int idxA = ((lane & 16) << 3) + r15 * 4;   // src = 32*(h&1) + r15
    const int idxB = idxA + 64;                      // src += 16
    const bool hiHalf = (lane & 32) != 0;

    #pragma unroll 1
    for (int t = 0; t < TILES; ++t) {
        const int pb = blkbase + t * MBLK;
        if (F16TAB && t + 1 < TILES) issueGather(pb + MBLK);  // hidden under compute
        const int slot = t & 1;

        f16x2 accP[8][2];
        #pragma unroll
        for (int ct = 0; ct < 8; ++ct)
            #pragma unroll
            for (int s = 0; s < 2; ++s) accP[ct][s] = (f16x2){(_Float16)0.f, (_Float16)0.f};

        #pragma unroll 1
        for (int lvl = 0; lvl < NLVL; ++lvl) {
            const bool lastAll = (t == TILES - 1) && (lvl == NLVL - 1);
            if (!lastAll) stage((lvl + 1) & 3);     // wraps: lvl3 stages panel0 for next tile
            const _Float16* wp = &wbuf[lvl & 1][0];

            // g as B-frag: lanes 0-15 carry the 8 features
            f16x8 gB;
            {
                f16x8 z;
                #pragma unroll
                for (int q = 0; q < 8; ++q) z[q] = (_Float16)0.f;
                if (lane < 16)
                    z = *(const f16x8*)&gS[slot][lvl][wv * 16 + lane][0];
                gB = z;
            }

            // ---- phase B: C1 = Ws'^T(A) x X(B) + bs'; xn = sin01(c1) + sin01(c2) ----
            unsigned int P[4][2];
            #pragma unroll
            for (int ct = 0; ct < 4; ++ct) {
                const int i0 = ((ct * 16 + r15) * 64 + hi4 * 8) ^ ((r15 & 7) << 3);
                f16x8 A0 = *(const f16x8*)&wp[i0];
                f16x8 A1 = *(const f16x8*)&wp[i0 ^ 32];
                f16x8 Af;
                #pragma unroll
                for (int q = 0; q < 8; ++q) Af[q] = (_Float16)0.f;
                if (lane < 16)
                    Af = *(const f16x8*)&wp[4096 + (ct * 16 + lane) * 8];
                float4 bs4 = *(const float4*)&bs[lvl * 64 + ct * 16 + hi4 * 4];

                f32x4 c1 = {bs4.x * SFOLD, bs4.y * SFOLD, bs4.z * SFOLD, bs4.w * SFOLD};
                c1 = __builtin_amdgcn_mfma_f32_16x16x32_f16(A0, Xb[0], c1, 0, 0, 0);
                c1 = __builtin_amdgcn_mfma_f32_16x16x32_f16(A1, Xb[1], c1, 0, 0, 0);
                f32x4 c2 = {0.f, 0.f, 0.f, 0.f};
                c2 = __builtin_amdgcn_mfma_f32_16x16x32_f16(Af, gB, c2, 0, 0, 0);

                P[ct][0] = pk16(fsin01(c1[0]) + fsin01(c2[0]),
                                fsin01(c1[1]) + fsin01(c2[1]));
                P[ct][1] = pk16(fsin01(c1[2]) + fsin01(c2[2]),
                                fsin01(c1[3]) + fsin01(c2[3]));
            }

            // ---- in-register exchange: C-layout -> B-frag layout ----
            #pragma unroll
            for (int kb = 0; kb < 2; ++kb) {
                unsigned int w[4];
                #pragma unroll
                for (int m = 0; m < 4; ++m) {
                    int idx = (m < 2) ? idxA : idxB;
                    int lo = __builtin_amdgcn_ds_bpermute(idx, (int)P[2 * kb + 0][m & 1]);
                    int hi = __builtin_amdgcn_ds_bpermute(idx, (int)P[2 * kb + 1][m & 1]);
                    w[m] = (unsigned int)(hiHalf ? hi : lo);
                }
                Xb[kb] = __builtin_bit_cast(f16x8, (u32x4){w[0], w[1], w[2], w[3]});
            }

            // ---- phase C: C = X(A) x Wout'(B) + bout'; out += sin01(c) ----
            #pragma unroll
            for (int ct = 0; ct < 8; ++ct) {
                const _Float16* bp = &wp[4608 + (ct * 2) * 512 + hi4 * 128 + r15 * 8];
                f16x8 B0 = *(const f16x8*)bp;
                f16x8 B1 = *(const f16x8*)(bp + 512);
                float bov = bout[lvl * 128 + ct * 16 + r15] * SFOLD;
                f32x4 c = {bov, bov, bov, bov};
                c = __builtin_amdgcn_mfma_f32_16x16x32_f16(Xb[0], B0, c, 0, 0, 0);
                c = __builtin_amdgcn_mfma_f32_16x16x32_f16(Xb[1], B1, c, 0, 0, 0);
                accP[ct][0] = accP[ct][0] +
                    __builtin_bit_cast(f16x2, pk16(fsin01(c[0]), fsin01(c[1])));
                accP[ct][1] = accP[ct][1] +
                    __builtin_bit_cast(f16x2, pk16(fsin01(c[2]), fsin01(c[3])));
            }

            if (!lastAll) __syncthreads();   // wbuf readers done; next panel staged
        }

        // ---- store tile t (coalesced over r15) ----
        #pragma unroll
        for (int s = 0; s < 2; ++s)
            #pragma unroll
            for (int r2 = 0; r2 < 2; ++r2) {
                int row = pb + wv * 16 + hi4 * 4 + s * 2 + r2;
                #pragma unroll
                for (int ct = 0; ct < 8; ++ct) {
                    float v = (float)accP[ct][s][r2];
                    __builtin_nontemporal_store(v, &out[(size_t)row * 128 + ct * 16 + r15]);
                }
            }

        // ---- tile boundary: finish next tile's g + layer0 ----
        if (t + 1 < TILES) {
            if (F16TAB) interpStore((t + 1) & 1);
            else        gatherF32(pb + MBLK, (t + 1) & 1);
            layer0(pb + MBLK);
            __syncthreads();   // gS[(t+1)&1] visible; panel0 already staged at lvl3
        }
    }
}

extern "C" void kernel_launch(void* const* d_in, const int* in_sizes, int n_in,
                              void* d_out, int out_size, void* d_ws, size_t ws_size,
                              hipStream_t stream) {
    const float* in_pos = (const float*)d_in[0];
    const float* table  = (const float*)d_in[1];
    const float* ffn    = (const float*)d_in[2];
    const float* W0     = (const float*)d_in[3];
    const float* b0     = (const float*)d_in[4];
    const float* Ws     = (const float*)d_in[5];
    const float* bs     = (const float*)d_in[6];
    const float* Wout   = (const float*)d_in[7];
    const float* bout   = (const float*)d_in[8];
    float* out = (float*)d_out;
    _Float16* ws = (_Float16*)d_ws;

    const int n = in_sizes[0] / 3;    // 524288
    // ws f16 layout: [0,51200) panels | [65536, +16.7M) tab16
    const size_t tabElems = (size_t)NLVL * TSIZE * 8;            // 16,777,216
    const size_t need1 = (65536u + tabElems) * 2u;               // ~33.7 MB
    _Float16* tab16 = ws + 65536;

    prep_weights<<<dim3(200), dim3(256), 0, stream>>>(Ws, Wout, ffn, ws);

    const int grid = n / (MBLK * TILES);   // 1024
    if (ws_size >= need1) {
        prep_table<<<dim3(tabElems / 256), dim3(256), 0, stream>>>(table, tab16);
        ffb_main<true><<<dim3(grid), dim3(512), 0, stream>>>(
            in_pos, table, tab16, W0, b0, bs, bout, ws, out);
    } else {
        ffb_main<false><<<dim3(grid), dim3(512), 0, stream>>>(
            in_pos, table, tab16, W0, b0, bs, bout, ws, out);
    }
}

// Round 17
// 226.483 us; speedup vs baseline: 1.4065x; 1.4065x over previous
//
#include <hip/hip_runtime.h>
#include <cstdint>
#include <cstddef>

#define NLVL 4
#define TSIZE (1u << 19)
#define NH 64
#define NOUT 128
#define MBLK 128           // points per workgroup; 8 waves x 16 points
#define PANEL 12800        // f16 elems per level panel: WsA 4096 | Ff 512 | WoB 8192
#define SFOLD 4.774648292756860f   // 30/(2*pi), folded into Ws/Wout/bs/bout

typedef _Float16 f16x8 __attribute__((ext_vector_type(8)));
typedef _Float16 f16x2 __attribute__((ext_vector_type(2)));
typedef float f32x4 __attribute__((ext_vector_type(4)));
typedef unsigned short u16x8 __attribute__((ext_vector_type(8)));
typedef unsigned short u16x4 __attribute__((ext_vector_type(4)));
typedef unsigned int u32x4 __attribute__((ext_vector_type(4)));

// sin(2*pi*x): fract then v_sin (input in revolutions)
__device__ __forceinline__ float fsin01(float x) {
    return __builtin_amdgcn_sinf(__builtin_amdgcn_fractf(x));
}
__device__ __forceinline__ unsigned short h2u(_Float16 h) {
    return __builtin_bit_cast(unsigned short, h);
}
__device__ __forceinline__ unsigned int pk16(float a, float b) {
    return __builtin_bit_cast(unsigned int, __builtin_amdgcn_cvt_pkrtz(a, b));
}
// async global->LDS, 16B per lane; lds dest = wave-uniform base + lane*16
__device__ __forceinline__ void gl_lds16(const _Float16* g, _Float16* l) {
    __builtin_amdgcn_global_load_lds(
        (const __attribute__((address_space(1))) void*)g,
        (__attribute__((address_space(3))) void*)l, 16, 0, 0);
}

// ---- prep 1: weights -> per-level packed panels in d_ws (f16), scales folded ----
// panel[lvl] (f16 offsets): [0,4096)  WsA*S: (c*64+k) ^ ((c&7)<<3)  (swizzled A-frags)
//                           [4096,4608) Ff/4096: c*8+k
//                           [4608,12800) WoB*S: (ct*2+kb)*512 + hi4*128 + r15*8 + j
__global__ void prep_weights(const float* __restrict__ Ws,
                             const float* __restrict__ Wout,
                             const float* __restrict__ ffn,
                             _Float16* __restrict__ ws)
{
    int i = blockIdx.x * 256 + threadIdx.x;
    if (i < 16384) {                       // Ws [4][64 k][64 c]
        int l = i >> 12, r = i & 4095, k = r >> 6, c = r & 63;
        ws[l * PANEL + ((c * 64 + k) ^ ((c & 7) << 3))] = (_Float16)(Ws[i] * SFOLD);
    } else if (i < 18432) {                // ffn [4][8 k][64 c]
        int j = i - 16384;
        int l = j >> 9, r = j & 511, k = r >> 6, c = r & 63;
        ws[l * PANEL + 4096 + c * 8 + k] = (_Float16)(ffn[j] * 0.000244140625f);
    } else if (i < 51200) {                // Wout [4][64 k][128 c]
        int j = i - 18432;
        int l = j >> 13, rem = j & 8191, k = rem >> 7, c = rem & 127;
        int ct = c >> 4, r15 = c & 15, kb = k >> 5, hi4 = (k >> 3) & 3, jj = k & 7;
        ws[l * PANEL + 4608 + (ct * 2 + kb) * 512 + hi4 * 128 + r15 * 8 + jj] =
            (_Float16)(Wout[j] * SFOLD);
    }
}

// ---- prep 2: table f32 -> f16 * 4096, vectorized 4 elems/thread ----
__global__ __launch_bounds__(256) void prep_table(const float* __restrict__ table,
                                                  _Float16* __restrict__ tab16)
{
    int i = blockIdx.x * 256 + threadIdx.x;            // over 4-elem groups: 4,194,304
    f32x4 v = __builtin_nontemporal_load((const f32x4*)table + i);
    u16x4 r;
    r[0] = h2u((_Float16)(v[0] * 4096.f));
    r[1] = h2u((_Float16)(v[1] * 4096.f));
    r[2] = h2u((_Float16)(v[2] * 4096.f));
    r[3] = h2u((_Float16)(v[3] * 4096.f));
    *((u16x4*)tab16 + i) = r;                          // plain store: warms L2/L3
}

template <bool F16TAB>
__global__ __launch_bounds__(512, 2)
void ffb_main(const float* __restrict__ in_pos,
              const float* __restrict__ table,
              const _Float16* __restrict__ tab16,
              const float* __restrict__ W0,
              const float* __restrict__ b0,
              const float* __restrict__ bs,
              const float* __restrict__ bout,
              const _Float16* __restrict__ wsg,
              float* __restrict__ out)
{
    __shared__ __align__(16) _Float16 wbuf[2][PANEL];            // 51200 B dbuf panels
    __shared__ __align__(16) unsigned short gS[NLVL][MBLK][8];   // 8192 B, g * 4096

    const int tid = threadIdx.x;
    const int pbase = blockIdx.x * MBLK;
    const int lane = tid & 63;
    const int wv = tid >> 6;
    const int r15 = lane & 15;
    const int hi4 = lane >> 4;

    // async panel staging (alternating dbuf); issue early so DMA overlaps gather
    auto stage = [&](int l) {
        const _Float16* src = wsg + l * PANEL;
        _Float16* dst = &wbuf[l & 1][0];
        #pragma unroll
        for (int i = 0; i < 3; ++i)
            gl_lds16(src + (i * 512 + tid) * 8, dst + (i * 512 + (tid & ~63)) * 8);
        if (tid < 64)
            gl_lds16(src + (1536 + tid) * 8, dst + 1536 * 8);
    };
    stage(0);

    // ---------- stage 1: each thread gathers one (point, level) ----------
    {
        const int p = tid & (MBLK - 1);
        const int lv = tid >> 7;
        const float px = in_pos[3 * (pbase + p) + 0];
        const float py = in_pos[3 * (pbase + p) + 1];
        const float pz = in_pos[3 * (pbase + p) + 2];
        const float qx = (px + 1.f) * 0.5f, qy = (py + 1.f) * 0.5f, qz = (pz + 1.f) * 0.5f;
        const uint32_t P1 = 2654435761u, P2 = 805459861u;

        const float res = (float)(16 << lv);
        float gx = qx * res, gy = qy * res, gz = qz * res;
        float fx0 = floorf(gx), fy0 = floorf(gy), fz0 = floorf(gz);
        float fx = gx - fx0, fy = gy - fy0, fz = gz - fz0;
        uint32_t ux = (uint32_t)fx0, uy = (uint32_t)fy0, uz = (uint32_t)fz0;
        uint32_t hx0 = ux, hx1 = ux + 1u;
        uint32_t hy0 = uy * P1, hy1 = hy0 + P1;
        uint32_t hz0 = uz * P2, hz1 = hz0 + P2;

        uint32_t hh[8];
        float    wgt[8];
        #pragma unroll
        for (int c = 0; c < 8; ++c) {
            hh[c] = (((c & 4) ? hx1 : hx0) ^ ((c & 2) ? hy1 : hy0)
                     ^ ((c & 1) ? hz1 : hz0)) & (TSIZE - 1u);
            wgt[c] = ((c & 4) ? fx : 1.f - fx) * ((c & 2) ? fy : 1.f - fy)
                   * ((c & 1) ? fz : 1.f - fz);
        }

        if (F16TAB) {
            const _Float16* tl = tab16 + (size_t)lv * TSIZE * 8;
            u16x8 vv[8];
            #pragma unroll
            for (int c = 0; c < 8; ++c)
                vv[c] = *(const u16x8*)(tl + (size_t)hh[c] * 8);
            f16x2 acc2[4];
            #pragma unroll
            for (int q = 0; q < 4; ++q) acc2[q] = (f16x2){(_Float16)0.f, (_Float16)0.f};
            #pragma unroll
            for (int c = 0; c < 8; ++c) {
                _Float16 wh = (_Float16)wgt[c];
                f16x2 ww = {wh, wh};
                const f16x2* vp = (const f16x2*)&vv[c];
                #pragma unroll
                for (int q = 0; q < 4; ++q) acc2[q] = acc2[q] + ww * vp[q];
            }
            *(u16x8*)&gS[lv][p][0] = *(u16x8*)&acc2[0];
        } else {
            const float* tl = table + (size_t)lv * TSIZE * 8;
            float g[8];
            #pragma unroll
            for (int q = 0; q < 8; ++q) g[q] = 0.f;
            #pragma unroll
            for (int c = 0; c < 8; ++c) {
                const f32x4* fp = (const f32x4*)(tl + (size_t)hh[c] * 8);
                f32x4 va = fp[0], vb = fp[1];
                float w = wgt[c];
                g[0] = fmaf(w, va[0], g[0]); g[1] = fmaf(w, va[1], g[1]);
                g[2] = fmaf(w, va[2], g[2]); g[3] = fmaf(w, va[3], g[3]);
                g[4] = fmaf(w, vb[0], g[4]); g[5] = fmaf(w, vb[1], g[5]);
                g[6] = fmaf(w, vb[2], g[6]); g[7] = fmaf(w, vb[3], g[7]);
            }
            u16x8 gv;
            #pragma unroll
            for (int q = 0; q < 8; ++q)
                gv[q] = h2u((_Float16)(g[q] * 4096.f));
            *(u16x8*)&gS[lv][p][0] = gv;
        }
    }

    // ---------- layer0 directly into B-frags (folded: sin(30a) = fsin01(a*S)) ----------
    f16x8 Xb[2];
    {
        const int pp = pbase + wv * 16 + r15;
        const float lpx = in_pos[3 * pp + 0];
        const float lpy = in_pos[3 * pp + 1];
        const float lpz = in_pos[3 * pp + 2];
        #pragma unroll
        for (int kb = 0; kb < 2; ++kb) {
            f16x8 v;
            #pragma unroll
            for (int j = 0; j < 8; ++j) {
                const int f = kb * 32 + hi4 * 8 + j;
                float a = b0[f] + lpx * W0[f] + lpy * W0[64 + f] + lpz * W0[128 + f];
                v[j] = (_Float16)fsin01(a * SFOLD);
            }
            Xb[kb] = v;
        }
    }
    __syncthreads();   // gS visible + panel 0 staged (barrier drains vmcnt)

    // bpermute indices (byte addressing)
    const int idxA = ((lane & 16) << 3) + r15 * 4;   // src = 32*(h&1) + r15
    const int idxB = idxA + 64;                      // src += 16
    const bool hiHalf = (lane & 32) != 0;

    f16x2 accP[8][2];
    #pragma unroll
    for (int ct = 0; ct < 8; ++ct)
        #pragma unroll
        for (int s = 0; s < 2; ++s) accP[ct][s] = (f16x2){(_Float16)0.f, (_Float16)0.f};

    #pragma unroll 1
    for (int lvl = 0; lvl < NLVL; ++lvl) {
        if (lvl < NLVL - 1) stage(lvl + 1);         // prefetch next panel (other buffer)
        const _Float16* wp = &wbuf[lvl & 1][0];

        // g as B-frag: only lanes 0-15 nonzero
        f16x8 gB;
        {
            f16x8 z;
            #pragma unroll
            for (int q = 0; q < 8; ++q) z[q] = (_Float16)0.f;
            if (lane < 16)
                z = *(const f16x8*)&gS[lvl][wv * 16 + lane][0];
            gB = z;
        }

        // ---- phase B: C1 = Ws'^T(A) x X(B) + bs'; xn = sin01(c1) + sin01(c2) ----
        unsigned int P[4][2];
        #pragma unroll
        for (int ct = 0; ct < 4; ++ct) {
            const int i0 = ((ct * 16 + r15) * 64 + hi4 * 8) ^ ((r15 & 7) << 3);
            f16x8 A0 = *(const f16x8*)&wp[i0];
            f16x8 A1 = *(const f16x8*)&wp[i0 ^ 32];
            f16x8 Af;
            #pragma unroll
            for (int q = 0; q < 8; ++q) Af[q] = (_Float16)0.f;
            if (lane < 16)
                Af = *(const f16x8*)&wp[4096 + (ct * 16 + lane) * 8];
            float4 bs4 = *(const float4*)&bs[lvl * 64 + ct * 16 + hi4 * 4];

            f32x4 c1 = {bs4.x * SFOLD, bs4.y * SFOLD, bs4.z * SFOLD, bs4.w * SFOLD};
            c1 = __builtin_amdgcn_mfma_f32_16x16x32_f16(A0, Xb[0], c1, 0, 0, 0);
            c1 = __builtin_amdgcn_mfma_f32_16x16x32_f16(A1, Xb[1], c1, 0, 0, 0);
            f32x4 c2 = {0.f, 0.f, 0.f, 0.f};
            c2 = __builtin_amdgcn_mfma_f32_16x16x32_f16(Af, gB, c2, 0, 0, 0);

            P[ct][0] = pk16(fsin01(c1[0]) + fsin01(c2[0]),
                            fsin01(c1[1]) + fsin01(c2[1]));
            P[ct][1] = pk16(fsin01(c1[2]) + fsin01(c2[2]),
                            fsin01(c1[3]) + fsin01(c2[3]));
        }

        // ---- in-register exchange: C-layout -> B-frag layout ----
        #pragma unroll
        for (int kb = 0; kb < 2; ++kb) {
            unsigned int w[4];
            #pragma unroll
            for (int m = 0; m < 4; ++m) {
                int idx = (m < 2) ? idxA : idxB;
                int lo = __builtin_amdgcn_ds_bpermute(idx, (int)P[2 * kb + 0][m & 1]);
                int hi = __builtin_amdgcn_ds_bpermute(idx, (int)P[2 * kb + 1][m & 1]);
                w[m] = (unsigned int)(hiHalf ? hi : lo);
            }
            Xb[kb] = __builtin_bit_cast(f16x8, (u32x4){w[0], w[1], w[2], w[3]});
        }

        // ---- phase C: C = X(A) x Wout'(B) + bout'; out += sin01(c) ----
        #pragma unroll
        for (int ct = 0; ct < 8; ++ct) {
            const _Float16* bp = &wp[4608 + (ct * 2) * 512 + hi4 * 128 + r15 * 8];
            f16x8 B0 = *(const f16x8*)bp;
            f16x8 B1 = *(const f16x8*)(bp + 512);
            float bov = bout[lvl * 128 + ct * 16 + r15] * SFOLD;
            f32x4 c = {bov, bov, bov, bov};
            c = __builtin_amdgcn_mfma_f32_16x16x32_f16(Xb[0], B0, c, 0, 0, 0);
            c = __builtin_amdgcn_mfma_f32_16x16x32_f16(Xb[1], B1, c, 0, 0, 0);
            accP[ct][0] = accP[ct][0] +
                __builtin_bit_cast(f16x2, pk16(fsin01(c[0]), fsin01(c[1])));
            accP[ct][1] = accP[ct][1] +
                __builtin_bit_cast(f16x2, pk16(fsin01(c[2]), fsin01(c[3])));
        }

        if (lvl < NLVL - 1) __syncthreads();   // all read wp; next panel staged
    }

    // ---- store: row=point=pbase+16wv+hi4*4+r, col=ct*16+r15 (coalesced) ----
    #pragma unroll
    for (int s = 0; s < 2; ++s)
        #pragma unroll
        for (int r2 = 0; r2 < 2; ++r2) {
            int row = pbase + wv * 16 + hi4 * 4 + s * 2 + r2;
            #pragma unroll
            for (int ct = 0; ct < 8; ++ct) {
                float v = (float)accP[ct][s][r2];
                __builtin_nontemporal_store(v, &out[(size_t)row * 128 + ct * 16 + r15]);
            }
        }
}

extern "C" void kernel_launch(void* const* d_in, const int* in_sizes, int n_in,
                              void* d_out, int out_size, void* d_ws, size_t ws_size,
                              hipStream_t stream) {
    const float* in_pos = (const float*)d_in[0];
    const float* table  = (const float*)d_in[1];
    const float* ffn    = (const float*)d_in[2];
    const float* W0     = (const float*)d_in[3];
    const float* b0     = (const float*)d_in[4];
    const float* Ws     = (const float*)d_in[5];
    const float* bs     = (const float*)d_in[6];
    const float* Wout   = (const float*)d_in[7];
    const float* bout   = (const float*)d_in[8];
    float* out = (float*)d_out;
    _Float16* ws = (_Float16*)d_ws;

    const int n = in_sizes[0] / 3;    // 524288
    // ws f16 layout: [0,51200) panels | [65536, +16.7M) tab16
    const size_t tabElems = (size_t)NLVL * TSIZE * 8;            // 16,777,216
    const size_t need1 = (65536u + tabElems) * 2u;               // ~33.7 MB
    _Float16* tab16 = ws + 65536;

    prep_weights<<<dim3(200), dim3(256), 0, stream>>>(Ws, Wout, ffn, ws);

    if (ws_size >= need1) {
        prep_table<<<dim3(tabElems / 1024), dim3(256), 0, stream>>>(table, tab16);
        ffb_main<true><<<dim3(n / MBLK), dim3(512), 0, stream>>>(
            in_pos, table, tab16, W0, b0, bs, bout, ws, out);
    } else {
        ffb_main<false><<<dim3(n / MBLK), dim3(512), 0, stream>>>(
            in_pos, table, tab16, W0, b0, bs, bout, ws, out);
    }
}